// Round 3
// baseline (241.715 us; speedup 1.0000x reference)
//
#include <hip/hip_runtime.h>

// Problem constants (from reference: shape (32,1,512,512) fp32)
#define BATCH 32
#define H 512
#define W 512
#define N_TOT (BATCH * H * W)   // 8388608

// No-LDS version: each thread owns an 8-wide x 2-tall output patch and loads
// its own 16-wide x 4-tall input window per image with aligned float4 loads.
// Halo re-reads hit L1/L2 (≈2x L2 traffic, ~200 MB << 34.5 TB/s); HBM stays
// at the ~100 MB ideal. No barriers, no LDS bank conflicts, pure
// load->compute dataflow.
//
// Block = 256 threads = 64 thread-cols (full 512-px width) x 4 row-pairs
// -> one block covers a 512x8 slab. Grid = 64 slabs x 32 batches = 2048.

__device__ __forceinline__ void sobel_8x2(const float* __restrict__ p,
                                          int rowbase0, int x0, int tx,
                                          int y0, float sob[2][8])
{
    // rows y0-1 .. y0+2; cols x0-4 .. x0+11 (aligned float4 segments).
    float h1[4][8], h2[4][8];
#pragma unroll
    for (int rr = 0; rr < 4; ++rr) {
        const int yy = y0 - 1 + rr;
        const bool rv = (unsigned)yy < (unsigned)H;     // wave-uniform
        const float* row = p + rowbase0 + rr * W;       // = base + yy*W + x0
        const float4 z = make_float4(0.f, 0.f, 0.f, 0.f);
        const float4 s0 = (rv && tx > 0)  ? *reinterpret_cast<const float4*>(row - 4) : z;
        const float4 s1 = rv              ? *reinterpret_cast<const float4*>(row)     : z;
        const float4 s2 = rv              ? *reinterpret_cast<const float4*>(row + 4) : z;
        const float4 s3 = (rv && tx < 63) ? *reinterpret_cast<const float4*>(row + 8) : z;
        const float v[16] = {s0.x, s0.y, s0.z, s0.w, s1.x, s1.y, s1.z, s1.w,
                             s2.x, s2.y, s2.z, s2.w, s3.x, s3.y, s3.z, s3.w};
        // logical col j <-> global col x0-4+j; output col c centered at v[4+c]
#pragma unroll
        for (int c = 0; c < 8; ++c) {
            h1[rr][c] = v[c + 5] - v[c + 3];                      // [-1,0,1]
            h2[rr][c] = v[c + 3] + 2.f * v[c + 4] + v[c + 5];     // [1,2,1]
        }
    }
#pragma unroll
    for (int o = 0; o < 2; ++o)
#pragma unroll
        for (int c = 0; c < 8; ++c) {
            const float gx = h1[o][c] + 2.f * h1[o + 1][c] + h1[o + 2][c];
            const float gy = h2[o][c] - h2[o + 2][c];
            sob[o][c] = fabsf(gx) + fabsf(gy);
        }
}

__global__ __launch_bounds__(256, 4)
void fusion_loss_kernel(const float* __restrict__ A,
                        const float* __restrict__ B,
                        const float* __restrict__ F,
                        const int* __restrict__ scheme_arr,
                        float* __restrict__ out)
{
    __shared__ float red[4];

    const int t   = threadIdx.x;
    const int tx  = t & 63;                 // thread col group; one wave = one ty
    const int ty  = t >> 6;                 // row pair 0..3
    const int b   = blockIdx.y;
    const int x0  = tx << 3;
    const int y0  = (blockIdx.x << 3) + (ty << 1);
    const int base = b * (H * W);
    const int scheme = scheme_arr[b];

    float acc = 0.f;

    // ---- l_loss mini-pass: center 8x2 patch, guaranteed in-bounds; these
    //      lines are re-read by the sobel passes below (L1 hits). ----
#pragma unroll
    for (int rr = 0; rr < 2; ++rr) {
        const int ro = base + (y0 + rr) * W + x0;
        const float4 a0 = *reinterpret_cast<const float4*>(A + ro);
        const float4 a1 = *reinterpret_cast<const float4*>(A + ro + 4);
        const float4 b0 = *reinterpret_cast<const float4*>(B + ro);
        const float4 b1 = *reinterpret_cast<const float4*>(B + ro + 4);
        const float4 f0 = *reinterpret_cast<const float4*>(F + ro);
        const float4 f1 = *reinterpret_cast<const float4*>(F + ro + 4);
        const float av[8] = {a0.x, a0.y, a0.z, a0.w, a1.x, a1.y, a1.z, a1.w};
        const float bv[8] = {b0.x, b0.y, b0.z, b0.w, b1.x, b1.y, b1.z, b1.w};
        const float fv[8] = {f0.x, f0.y, f0.z, f0.w, f1.x, f1.y, f1.z, f1.w};
#pragma unroll
        for (int c = 0; c < 8; ++c) {
            const float ab = (scheme == 0) ? 0.5f * (av[c] + bv[c])
                           : (scheme == 1) ? fmaxf(av[c], bv[c])
                           : 0.f;
            acc += fabsf(ab - fv[c]);
        }
    }

    // ---- grad_loss: per-image separable Sobel on the 16x4 window ----
    const int rowbase0 = base + (y0 - 1) * W + x0;
    float sobA[2][8], sobB[2][8], sobF[2][8];
    sobel_8x2(A, rowbase0, x0, tx, y0, sobA);
    sobel_8x2(B, rowbase0, x0, tx, y0, sobB);
    sobel_8x2(F, rowbase0, x0, tx, y0, sobF);
#pragma unroll
    for (int o = 0; o < 2; ++o)
#pragma unroll
        for (int c = 0; c < 8; ++c)
            acc += fabsf(sobF[o][c] - fmaxf(sobA[o][c], sobB[o][c]));

    // ---- reduction: 64-lane shuffle, cross-wave via LDS, one atomic ----
#pragma unroll
    for (int off = 32; off > 0; off >>= 1)
        acc += __shfl_down(acc, off, 64);
    if ((t & 63) == 0) red[t >> 6] = acc;
    __syncthreads();
    if (t == 0)
        atomicAdd(out, (red[0] + red[1] + red[2] + red[3]) * (1.0f / (float)N_TOT));
}

extern "C" void kernel_launch(void* const* d_in, const int* in_sizes, int n_in,
                              void* d_out, int out_size, void* d_ws, size_t ws_size,
                              hipStream_t stream)
{
    const float* A = (const float*)d_in[0];
    const float* B = (const float*)d_in[1];
    const float* F = (const float*)d_in[2];
    const int* scheme = (const int*)d_in[3];
    float* out = (float*)d_out;

    // d_out is poisoned before every launch; zero it for the atomics.
    hipMemsetAsync(out, 0, sizeof(float), stream);

    dim3 grid(H / 8, BATCH);   // 64 slabs x 32 batches = 2048 blocks
    dim3 block(256);
    fusion_loss_kernel<<<grid, block, 0, stream>>>(A, B, F, scheme, out);
}

// Round 4
// 140.474 us; speedup vs baseline: 1.7207x; 1.7207x over previous
//
#include <hip/hip_runtime.h>

// Problem constants (from reference: shape (32,1,512,512) fp32)
#define BATCH 32
#define H 512
#define W 512
#define N_TOT (BATCH * H * W)   // 8388608

// No-LDS streaming kernel. Each thread owns an 8-wide x 2-tall output patch.
// A wave's 64 lanes span the full 512-px row, so the 1-px horizontal halo
// comes from neighbor lanes via __shfl (lane boundary == image boundary ==
// zero-pad; exact). Per sobel row each lane does just 2 aligned float4 loads.
// Images processed sequentially (A -> B -> running max -> F folded into acc)
// to keep peak live registers ~90 (round 3's launch_bounds(256,4) capped
// VGPRs at 64 and spilled 86 MB to scratch -- removed).

__device__ __forceinline__ void sobel_pass(const float* __restrict__ p,
                                           int base, int x0, int y0, int tx,
                                           float sob[2][8])
{
    float h1[4][8], h2[4][8];   // liveness-limited: peak 3 rows live
#pragma unroll
    for (int rr = 0; rr < 4; ++rr) {
        const int yy = y0 - 1 + rr;
        const bool rv = (unsigned)yy < (unsigned)H;   // wave-uniform
        const float* row = p + base + yy * W + x0;
        float4 s1 = make_float4(0.f, 0.f, 0.f, 0.f), s2 = s1;
        if (rv) {
            s1 = *reinterpret_cast<const float4*>(row);       // cols x0..x0+3
            s2 = *reinterpret_cast<const float4*>(row + 4);   // cols x0+4..x0+7
        }
        float lw = __shfl_up(s2.w, 1, 64);    // lane tx-1's col x0-1
        if (tx == 0)  lw = 0.f;               // image left edge: zero-pad
        float rw = __shfl_down(s1.x, 1, 64);  // lane tx+1's col x0+8
        if (tx == 63) rw = 0.f;               // image right edge: zero-pad
        // v[j] = col x0-1+j, j=0..9
        const float v[10] = {lw, s1.x, s1.y, s1.z, s1.w,
                             s2.x, s2.y, s2.z, s2.w, rw};
#pragma unroll
        for (int c = 0; c < 8; ++c) {
            h1[rr][c] = v[c + 2] - v[c];                    // row conv [-1,0,1]
            h2[rr][c] = v[c] + 2.f * v[c + 1] + v[c + 2];   // row conv [1,2,1]
        }
    }
#pragma unroll
    for (int o = 0; o < 2; ++o)
#pragma unroll
        for (int c = 0; c < 8; ++c) {
            const float gx = h1[o][c] + 2.f * h1[o + 1][c] + h1[o + 2][c];
            const float gy = h2[o][c] - h2[o + 2][c];
            sob[o][c] = fabsf(gx) + fabsf(gy);
        }
}

__global__ __launch_bounds__(256)
void fusion_loss_kernel(const float* __restrict__ A,
                        const float* __restrict__ B,
                        const float* __restrict__ F,
                        const int* __restrict__ scheme_arr,
                        float* __restrict__ out)
{
    __shared__ float red[4];

    const int t   = threadIdx.x;
    const int tx  = t & 63;                  // lane: column group (8 px each)
    const int ty  = t >> 6;                  // wave: row pair 0..3
    const int b   = blockIdx.y;
    const int x0  = tx << 3;
    const int y0  = (blockIdx.x << 3) + (ty << 1);
    const int base = b * (H * W);
    const int scheme = scheme_arr[b];

    float acc = 0.f;

    // ---- l_loss mini-pass: rows y0,y0+1, own 8 cols (in-bounds). These
    //      lines are re-read by the sobel passes -> L1 hits either way. ----
#pragma unroll
    for (int rr = 0; rr < 2; ++rr) {
        const int ro = base + (y0 + rr) * W + x0;
        const float4 a0 = *reinterpret_cast<const float4*>(A + ro);
        const float4 a1 = *reinterpret_cast<const float4*>(A + ro + 4);
        const float4 b0 = *reinterpret_cast<const float4*>(B + ro);
        const float4 b1 = *reinterpret_cast<const float4*>(B + ro + 4);
        const float4 f0 = *reinterpret_cast<const float4*>(F + ro);
        const float4 f1 = *reinterpret_cast<const float4*>(F + ro + 4);
        const float av[8] = {a0.x, a0.y, a0.z, a0.w, a1.x, a1.y, a1.z, a1.w};
        const float bv[8] = {b0.x, b0.y, b0.z, b0.w, b1.x, b1.y, b1.z, b1.w};
        const float fv[8] = {f0.x, f0.y, f0.z, f0.w, f1.x, f1.y, f1.z, f1.w};
#pragma unroll
        for (int c = 0; c < 8; ++c) {
            const float ab = (scheme == 0) ? 0.5f * (av[c] + bv[c])
                           : (scheme == 1) ? fmaxf(av[c], bv[c])
                           : 0.f;
            acc += fabsf(ab - fv[c]);
        }
    }

    // ---- grad_loss: sequential per-image sobel, running max, fold F ----
    float sobM[2][8], sobT[2][8];
    sobel_pass(A, base, x0, y0, tx, sobM);
    sobel_pass(B, base, x0, y0, tx, sobT);
#pragma unroll
    for (int o = 0; o < 2; ++o)
#pragma unroll
        for (int c = 0; c < 8; ++c)
            sobM[o][c] = fmaxf(sobM[o][c], sobT[o][c]);   // sobT dead here
    sobel_pass(F, base, x0, y0, tx, sobT);
#pragma unroll
    for (int o = 0; o < 2; ++o)
#pragma unroll
        for (int c = 0; c < 8; ++c)
            acc += fabsf(sobT[o][c] - sobM[o][c]);

    // ---- reduction: 64-lane shuffle, cross-wave via LDS, one atomic ----
#pragma unroll
    for (int off = 32; off > 0; off >>= 1)
        acc += __shfl_down(acc, off, 64);
    if ((t & 63) == 0) red[t >> 6] = acc;
    __syncthreads();
    if (t == 0)
        atomicAdd(out, (red[0] + red[1] + red[2] + red[3]) * (1.0f / (float)N_TOT));
}

extern "C" void kernel_launch(void* const* d_in, const int* in_sizes, int n_in,
                              void* d_out, int out_size, void* d_ws, size_t ws_size,
                              hipStream_t stream)
{
    const float* A = (const float*)d_in[0];
    const float* B = (const float*)d_in[1];
    const float* F = (const float*)d_in[2];
    const int* scheme = (const int*)d_in[3];
    float* out = (float*)d_out;

    // d_out is poisoned before every launch; zero it for the atomics.
    hipMemsetAsync(out, 0, sizeof(float), stream);

    dim3 grid(H / 8, BATCH);   // 64 row-slabs x 32 batches = 2048 blocks
    dim3 block(256);
    fusion_loss_kernel<<<grid, block, 0, stream>>>(A, B, F, scheme, out);
}